// Round 3
// baseline (473.092 us; speedup 1.0000x reference)
//
#include <hip/hip_runtime.h>
#include <stdint.h>

typedef unsigned short u16;
typedef unsigned int u32;
typedef __bf16 bf16x8_t __attribute__((ext_vector_type(8)));
typedef float f32x4_t __attribute__((ext_vector_type(4)));
typedef unsigned int u32x2 __attribute__((ext_vector_type(2)));
typedef unsigned int u32x4 __attribute__((ext_vector_type(4)));

union FragAB { bf16x8_t v; u32x2 q[2]; };
union Stage16 { u32x4 v; u16 e[8]; };

#define DEVFN static __device__ __forceinline__

DEVFN u16 f2bf(float f) {
    u32 x = __builtin_bit_cast(u32, f);
    return (u16)((x + 0x7fffu + ((x >> 16) & 1u)) >> 16);
}

DEVFN f32x4_t zero4() { f32x4_t z = {0.f, 0.f, 0.f, 0.f}; return z; }

// B=128, T=256, C=384, H=6, D=64; rows = B*T = 32768
#define SCALE_QK 0.051031036307982884f  /* 1/sqrt(384) */
#define NEG_BIG  -30000.0f

// ---------------------------------------------------------------- LayerNorm
__global__ __launch_bounds__(256) void ln_kernel(
        const float* __restrict__ in, const float* __restrict__ g,
        const float* __restrict__ b, u16* __restrict__ out)
{
    const int lane = threadIdx.x & 63;
    const int w = threadIdx.x >> 6;
    const int row = blockIdx.x * 4 + w;
    const float* rp = in + (size_t)row * 384;
    float v[6];
    float s = 0.f, sq = 0.f;
    #pragma unroll
    for (int j = 0; j < 6; j++) {
        v[j] = rp[lane + j * 64];
        s += v[j];
        sq += v[j] * v[j];
    }
    #pragma unroll
    for (int o = 32; o >= 1; o >>= 1) {
        s  += __shfl_xor(s, o);
        sq += __shfl_xor(sq, o);
    }
    const float mean = s * (1.f / 384.f);
    const float var = sq * (1.f / 384.f) - mean * mean;
    const float rs = rsqrtf(var + 1e-5f);
    u16* op = out + (size_t)row * 384;
    #pragma unroll
    for (int j = 0; j < 6; j++) {
        const int c = lane + j * 64;
        op[c] = f2bf((v[j] - mean) * rs * g[c] + b[c]);
    }
}

// ------------------------------------------------------- weight repack (bf16)
__global__ void qkv_w_kernel(const float* __restrict__ wq, const float* __restrict__ wk,
                             const float* __restrict__ wv, u16* __restrict__ bt)
{
    const int idx = blockIdx.x * 256 + threadIdx.x;
    if (idx >= 1152 * 384) return;
    const int j = idx / 384, c = idx % 384;
    const int which = j / 384;
    const int r = j % 384;
    const int h = r / 64, d = r % 64;
    const float* w = (which == 0) ? wq : (which == 1 ? wk : wv);
    bt[idx] = f2bf(w[(h * 384 + c) * 64 + d]);
}

__global__ void transpose_w_kernel(const float* __restrict__ w, u16* __restrict__ bt,
                                   int K, int N)
{
    const int idx = blockIdx.x * 256 + threadIdx.x;
    if (idx >= K * N) return;
    const int n = idx / K, k = idx % K;
    bt[idx] = f2bf(w[(size_t)k * N + n]);
}

// ---------------------------------------------------------------- GEMM
// C[M][N] = A[M][K] * Bt[N][K]^T  (+bias, +res, relu, bf16/f32 out)
// 128x128 tile, BK=64, 4 waves of 64x64. Reg-staged loads -> padded LDS.
template<bool HAS_BIAS, bool HAS_RES, bool RELU, bool OUT_BF16>
__global__ __launch_bounds__(256) void gemm_kernel(
        const u16* __restrict__ A, const u16* __restrict__ Bt,
        const float* __restrict__ bias, const float* __restrict__ res,
        void* __restrict__ Out, int M, int N, int K)
{
    __shared__ u16 As[128 * 72];   // +8 pad: row stride 144 B (16B-aligned)
    __shared__ u16 Bs[128 * 72];
    const int tid = threadIdx.x;
    const int lane = tid & 63;
    const int w = tid >> 6;
    const int tileN = blockIdx.x * 128;
    const int tileM = blockIdx.y * 128;
    (void)M;

    f32x4_t acc[4][4];
    #pragma unroll
    for (int i = 0; i < 4; i++)
        #pragma unroll
        for (int j = 0; j < 4; j++)
            acc[i][j] = zero4();

    const int m = lane & 15;
    const int g4 = (lane >> 4) * 4;        // elem offset of 4-elem k-group
    const int srow = tid >> 3;             // 0..31
    const int scol = (tid & 7) * 8;        // 0..56

    for (int k0 = 0; k0 < K; k0 += 64) {
        #pragma unroll
        for (int i = 0; i < 4; i++) {
            const int r = i * 32 + srow;
            u32x4 av = *(const u32x4*)(A  + (size_t)(tileM + r) * K + k0 + scol);
            u32x4 bv = *(const u32x4*)(Bt + (size_t)(tileN + r) * K + k0 + scol);
            *(u32x4*)(&As[r * 72 + scol]) = av;
            *(u32x4*)(&Bs[r * 72 + scol]) = bv;
        }
        __syncthreads();

        FragAB af[4][2], bfb[4][2];
        #pragma unroll
        for (int mi = 0; mi < 4; mi++) {
            const u16* rp = &As[((w >> 1) * 64 + mi * 16 + m) * 72];
            #pragma unroll
            for (int ks = 0; ks < 2; ks++) {
                af[mi][ks].q[0] = *(const u32x2*)(rp + ks * 32 + g4);
                af[mi][ks].q[1] = *(const u32x2*)(rp + ks * 32 + 16 + g4);
            }
        }
        #pragma unroll
        for (int ni = 0; ni < 4; ni++) {
            const u16* rp = &Bs[((w & 1) * 64 + ni * 16 + m) * 72];
            #pragma unroll
            for (int ks = 0; ks < 2; ks++) {
                bfb[ni][ks].q[0] = *(const u32x2*)(rp + ks * 32 + g4);
                bfb[ni][ks].q[1] = *(const u32x2*)(rp + ks * 32 + 16 + g4);
            }
        }
        #pragma unroll
        for (int ks = 0; ks < 2; ks++)
            #pragma unroll
            for (int mi = 0; mi < 4; mi++)
                #pragma unroll
                for (int ni = 0; ni < 4; ni++)
                    acc[mi][ni] = __builtin_amdgcn_mfma_f32_16x16x32_bf16(
                        af[mi][ks].v, bfb[ni][ks].v, acc[mi][ni], 0, 0, 0);
        __syncthreads();
    }

    // epilogue: D layout col=lane&15, row=(lane>>4)*4+reg  [verified m89]
    #pragma unroll
    for (int mi = 0; mi < 4; mi++) {
        #pragma unroll
        for (int ni = 0; ni < 4; ni++) {
            #pragma unroll
            for (int r = 0; r < 4; r++) {
                const int grow = tileM + (w >> 1) * 64 + mi * 16 + (lane >> 4) * 4 + r;
                const int gcol = tileN + (w & 1) * 64 + ni * 16 + (lane & 15);
                float v = acc[mi][ni][r];
                if (HAS_BIAS) v += bias[gcol];
                if (HAS_RES) v += res[(size_t)grow * N + gcol];
                if (RELU) v = fmaxf(v, 0.f);
                const size_t o = (size_t)grow * N + gcol;
                if (OUT_BF16) ((u16*)Out)[o] = f2bf(v);
                else ((float*)Out)[o] = v;
            }
        }
    }
}

// ---------------------------------------------------------------- attention
// one block per (local batch, head). qkv: [rows][1152] bf16 chunk (q|k|v per head),
// out: full [32768][384] bf16 base, rows offset by row0.
__global__ __launch_bounds__(256) void attn_kernel(
        const u16* __restrict__ qkv, u16* __restrict__ out, int row0)
{
    __shared__ u16 Kl[256 * 72];       // K rows, +8 pad
    __shared__ u16 Vt[64 * 264];       // V transposed [d][s], +8 pad
    __shared__ u16 Pl[4 * 16 * 264];   // per-wave P tile [16][256], +8 pad

    const int bi = blockIdx.x / 6, h = blockIdx.x % 6;
    const int tid = threadIdx.x, lane = tid & 63, w = tid >> 6;
    const u16* base = qkv + (size_t)bi * 256 * 1152 + h * 64;

    // stage K rows and V^T; each thread covers 8 bf16 = 16 B (u32x4)
    #pragma unroll
    for (int pass = 0; pass < 8; pass++) {
        const int s = pass * 32 + (tid >> 3);
        const int d8 = (tid & 7) * 8;
        const u16* krow = base + (size_t)s * 1152;
        *(u32x4*)(&Kl[s * 72 + d8]) = *(const u32x4*)(krow + 384 + d8);
        Stage16 vv;
        vv.v = *(const u32x4*)(krow + 768 + d8);
        #pragma unroll
        for (int j = 0; j < 8; j++) Vt[(d8 + j) * 264 + s] = vv.e[j];
    }
    __syncthreads();

    const int m = lane & 15;
    const int g4 = (lane >> 4) * 4;
    u16* pw = &Pl[w * 16 * 264];

    for (int p = 0; p < 4; p++) {
        const int rt = p * 4 + w;     // row-tile 0..15
        const int rp = rt * 16;
        const int nt = rt + 1;        // causal: col-tiles needed

        FragAB qa[2];
        const u16* qrow = base + (size_t)(rp + m) * 1152;
        #pragma unroll
        for (int ks = 0; ks < 2; ks++) {
            qa[ks].q[0] = *(const u32x2*)(qrow + ks * 32 + g4);
            qa[ks].q[1] = *(const u32x2*)(qrow + ks * 32 + 16 + g4);
        }

        f32x4_t sacc[16];
        #pragma unroll
        for (int ct = 0; ct < 16; ct++) {
            if (ct < nt) {
                sacc[ct] = zero4();
                #pragma unroll
                for (int ks = 0; ks < 2; ks++) {
                    FragAB kb;
                    const u16* kr = &Kl[(ct * 16 + m) * 72 + ks * 32 + g4];
                    kb.q[0] = *(const u32x2*)(kr);
                    kb.q[1] = *(const u32x2*)(kr + 16);
                    sacc[ct] = __builtin_amdgcn_mfma_f32_16x16x32_bf16(
                        qa[ks].v, kb.v, sacc[ct], 0, 0, 0);
                }
            }
        }

        const int rbase = rp + (lane >> 4) * 4;
        float mx[4] = {-1e30f, -1e30f, -1e30f, -1e30f};
        #pragma unroll
        for (int ct = 0; ct < 16; ct++) if (ct < nt) {
            #pragma unroll
            for (int r = 0; r < 4; r++) {
                float v = sacc[ct][r] * SCALE_QK;
                if (ct * 16 + m > rbase + r) v = NEG_BIG;
                sacc[ct][r] = v;
                mx[r] = fmaxf(mx[r], v);
            }
        }
        #pragma unroll
        for (int r = 0; r < 4; r++) {
            #pragma unroll
            for (int o = 1; o < 16; o <<= 1) mx[r] = fmaxf(mx[r], __shfl_xor(mx[r], o));
        }
        float sum[4] = {0.f, 0.f, 0.f, 0.f};
        #pragma unroll
        for (int ct = 0; ct < 16; ct++) if (ct < nt) {
            #pragma unroll
            for (int r = 0; r < 4; r++) {
                const float e = __expf(sacc[ct][r] - mx[r]);
                sacc[ct][r] = e;
                sum[r] += e;
            }
        }
        #pragma unroll
        for (int r = 0; r < 4; r++) {
            #pragma unroll
            for (int o = 1; o < 16; o <<= 1) sum[r] += __shfl_xor(sum[r], o);
        }
        float inv[4];
        #pragma unroll
        for (int r = 0; r < 4; r++) inv[r] = 1.f / sum[r];

        #pragma unroll
        for (int ct = 0; ct < 16; ct++) if (ct < nt) {
            #pragma unroll
            for (int r = 0; r < 4; r++)
                pw[((lane >> 4) * 4 + r) * 264 + ct * 16 + m] = f2bf(sacc[ct][r] * inv[r]);
        }
        if (nt & 1) {
            #pragma unroll
            for (int r = 0; r < 4; r++)
                pw[((lane >> 4) * 4 + r) * 264 + nt * 16 + m] = 0;
        }

        const int kpairs = (nt + 1) >> 1;
        f32x4_t oacc[4];
        #pragma unroll
        for (int ni = 0; ni < 4; ni++) oacc[ni] = zero4();
        #pragma unroll
        for (int kk = 0; kk < 8; kk++) if (kk < kpairs) {
            FragAB pa;
            const u16* pr = &pw[m * 264 + kk * 32 + g4];
            pa.q[0] = *(const u32x2*)(pr);
            pa.q[1] = *(const u32x2*)(pr + 16);
            #pragma unroll
            for (int ni = 0; ni < 4; ni++) {
                FragAB vb;
                const u16* vr = &Vt[(ni * 16 + m) * 264 + kk * 32 + g4];
                vb.q[0] = *(const u32x2*)(vr);
                vb.q[1] = *(const u32x2*)(vr + 16);
                oacc[ni] = __builtin_amdgcn_mfma_f32_16x16x32_bf16(
                    pa.v, vb.v, oacc[ni], 0, 0, 0);
            }
        }

        #pragma unroll
        for (int ni = 0; ni < 4; ni++) {
            #pragma unroll
            for (int r = 0; r < 4; r++) {
                const int t = rp + (lane >> 4) * 4 + r;
                out[((size_t)row0 + bi * 256 + t) * 384 + h * 64 + ni * 16 + m] =
                    f2bf(oacc[ni][r]);
            }
        }
    }
}

// ---------------------------------------------------------------- launch
extern "C" void kernel_launch(void* const* d_in, const int* in_sizes, int n_in,
                              void* d_out, int out_size, void* d_ws, size_t ws_size,
                              hipStream_t stream)
{
    (void)in_sizes; (void)n_in; (void)out_size;
    const float* x     = (const float*)d_in[0];
    const float* wq    = (const float*)d_in[1];
    const float* wk    = (const float*)d_in[2];
    const float* wv    = (const float*)d_in[3];
    const float* wproj = (const float*)d_in[4];
    const float* bproj = (const float*)d_in[5];
    const float* w1    = (const float*)d_in[6];
    const float* b1    = (const float*)d_in[7];
    const float* w2    = (const float*)d_in[8];
    const float* b2    = (const float*)d_in[9];
    const float* ln1g  = (const float*)d_in[10];
    const float* ln1b  = (const float*)d_in[11];
    const float* ln2g  = (const float*)d_in[12];
    const float* ln2b  = (const float*)d_in[13];
    float* out = (float*)d_out;

    // Fixed region: 28,704,768 B. Dynamic region holds qkv-chunk / mlp1-chunk.
    char* ws = (char*)d_ws;
    u16* hattn  = (u16*)(ws);                 // 25,165,824 B (LN1 out -> attn out -> LN2 out)
    u16* wqkvT  = (u16*)(ws + 25165824);      //    884,736 B
    u16* wprojT = (u16*)(ws + 26050560);      //    294,912 B
    u16* w1T    = (u16*)(ws + 26345472);      //  1,179,648 B
    u16* w2T    = (u16*)(ws + 27525120);      //  1,179,648 B
    char* dyn   = ws + 28704768;
    const size_t avail = (ws_size > (size_t)28704768) ? ws_size - (size_t)28704768 : (size_t)0;

    int na = 32, nm = 32;   // batch-chunk counts for qkv phase / mlp phase
    for (int n = 1; n <= 32; n <<= 1) if ((size_t)75497472  / n <= avail) { na = n; break; }
    for (int n = 1; n <= 32; n <<= 1) if ((size_t)100663296 / n <= avail) { nm = n; break; }

    qkv_w_kernel<<<1728, 256, 0, stream>>>(wq, wk, wv, wqkvT);
    transpose_w_kernel<<<576, 256, 0, stream>>>(wproj, wprojT, 384, 384);
    transpose_w_kernel<<<2304, 256, 0, stream>>>(w1, w1T, 384, 1536);
    transpose_w_kernel<<<2304, 256, 0, stream>>>(w2, w2T, 1536, 384);

    // LN1: x -> h (bf16)
    ln_kernel<<<8192, 256, 0, stream>>>(x, ln1g, ln1b, hattn);

    // QKV gemm + attention, chunked over batches; attn overlays h rows already consumed
    const int rows_a = 32768 / na, bat_a = 128 / na;
    u16* qkvc = (u16*)dyn;
    for (int c = 0; c < na; c++) {
        const int row0 = c * rows_a;
        gemm_kernel<false, false, false, true><<<dim3(9, rows_a / 128), 256, 0, stream>>>(
            hattn + (size_t)row0 * 384, wqkvT, nullptr, nullptr, qkvc, rows_a, 1152, 384);
        attn_kernel<<<bat_a * 6, 256, 0, stream>>>(qkvc, hattn, row0);
    }

    // proj + bias + residual(x) -> out (fp32)
    gemm_kernel<true, true, false, false><<<dim3(3, 256), 256, 0, stream>>>(
        hattn, wprojT, bproj, x, out, 32768, 384, 384);

    // LN2: out -> h (bf16)
    ln_kernel<<<8192, 256, 0, stream>>>(out, ln2g, ln2b, hattn);

    // MLP, chunked: fc1(+bias,relu) -> mlp1 chunk; fc2(+bias,+residual) -> out
    const int rows_m = 32768 / nm;
    u16* mlp1c = (u16*)dyn;
    for (int c = 0; c < nm; c++) {
        const int row0 = c * rows_m;
        gemm_kernel<true, false, true, true><<<dim3(12, rows_m / 128), 256, 0, stream>>>(
            hattn + (size_t)row0 * 384, w1T, b1, nullptr, mlp1c, rows_m, 1536, 384);
        gemm_kernel<true, true, false, false><<<dim3(3, rows_m / 128), 256, 0, stream>>>(
            mlp1c, w2T, b2, out + (size_t)row0 * 384, out + (size_t)row0 * 384,
            rows_m, 384, 1536);
    }
}

// Round 4
// 458.578 us; speedup vs baseline: 1.0316x; 1.0316x over previous
//
#include <hip/hip_runtime.h>
#include <stdint.h>

typedef unsigned short u16;
typedef unsigned int u32;
typedef __bf16 bf16x8_t __attribute__((ext_vector_type(8)));
typedef float f32x4_t __attribute__((ext_vector_type(4)));
typedef unsigned int u32x2 __attribute__((ext_vector_type(2)));
typedef unsigned int u32x4 __attribute__((ext_vector_type(4)));

union FragAB { bf16x8_t v; u32x2 q[2]; };
union Stage16 { u32x4 v; u16 e[8]; };

#define DEVFN static __device__ __forceinline__

DEVFN u16 f2bf(float f) {
    u32 x = __builtin_bit_cast(u32, f);
    return (u16)((x + 0x7fffu + ((x >> 16) & 1u)) >> 16);
}

DEVFN f32x4_t zero4() { f32x4_t z = {0.f, 0.f, 0.f, 0.f}; return z; }

typedef __attribute__((address_space(1))) void as1_void;
typedef __attribute__((address_space(3))) void as3_void;

#define GLOAD_LDS16(src, dst) \
    __builtin_amdgcn_global_load_lds((as1_void*)(void*)(src), (as3_void*)(dst), 16, 0, 0)

// B=128, T=256, C=384, H=6, D=64; rows = B*T = 32768
#define SCALE_QK 0.051031036307982884f  /* 1/sqrt(384) */
#define NEG_BIG  -30000.0f

// ---------------------------------------------------------------- LayerNorm
__global__ __launch_bounds__(256) void ln_kernel(
        const float* __restrict__ in, const float* __restrict__ g,
        const float* __restrict__ b, u16* __restrict__ out)
{
    const int lane = threadIdx.x & 63;
    const int w = threadIdx.x >> 6;
    const int row = blockIdx.x * 4 + w;
    const float* rp = in + (size_t)row * 384;
    float v[6];
    float s = 0.f, sq = 0.f;
    #pragma unroll
    for (int j = 0; j < 6; j++) {
        v[j] = rp[lane + j * 64];
        s += v[j];
        sq += v[j] * v[j];
    }
    #pragma unroll
    for (int o = 32; o >= 1; o >>= 1) {
        s  += __shfl_xor(s, o);
        sq += __shfl_xor(sq, o);
    }
    const float mean = s * (1.f / 384.f);
    const float var = sq * (1.f / 384.f) - mean * mean;
    const float rs = rsqrtf(var + 1e-5f);
    u16* op = out + (size_t)row * 384;
    #pragma unroll
    for (int j = 0; j < 6; j++) {
        const int c = lane + j * 64;
        op[c] = f2bf((v[j] - mean) * rs * g[c] + b[c]);
    }
}

// ------------------------------------------------------- weight repack (bf16)
__global__ void qkv_w_kernel(const float* __restrict__ wq, const float* __restrict__ wk,
                             const float* __restrict__ wv, u16* __restrict__ bt)
{
    const int idx = blockIdx.x * 256 + threadIdx.x;
    if (idx >= 1152 * 384) return;
    const int j = idx / 384, c = idx % 384;
    const int which = j / 384;
    const int r = j % 384;
    const int h = r / 64, d = r % 64;
    const float* w = (which == 0) ? wq : (which == 1 ? wk : wv);
    bt[idx] = f2bf(w[(h * 384 + c) * 64 + d]);
}

__global__ void transpose_w_kernel(const float* __restrict__ w, u16* __restrict__ bt,
                                   int K, int N)
{
    const int idx = blockIdx.x * 256 + threadIdx.x;
    if (idx >= K * N) return;
    const int n = idx / K, k = idx % K;
    bt[idx] = f2bf(w[(size_t)k * N + n]);
}

// ---------------------------------------------------------------- GEMM
// C[M][N] = A[M][K] * Bt[N][K]^T  (+bias, +res, relu, bf16/f32 out)
// 128x128 tile, BK=64, 4 waves of 64x64.
// global_load_lds width-16 staging: linear LDS dest, source 16B-chunk index
// pre-XORed with (row&7); reads XOR the same -> involution (rule #21).
template<bool HAS_BIAS, bool HAS_RES, bool RELU, bool OUT_BF16>
__global__ __launch_bounds__(256) void gemm_kernel(
        const u16* __restrict__ A, const u16* __restrict__ Bt,
        const float* __restrict__ bias, const float* __restrict__ res,
        void* __restrict__ Out, int M, int N, int K)
{
    __shared__ u16 As[128 * 64];
    __shared__ u16 Bs[128 * 64];
    const int tid = threadIdx.x;
    const int lane = tid & 63;
    const int w = tid >> 6;
    const int tileN = blockIdx.x * 128;
    const int tileM = blockIdx.y * 128;
    (void)M;

    f32x4_t acc[4][4];
    #pragma unroll
    for (int i = 0; i < 4; i++)
        #pragma unroll
        for (int j = 0; j < 4; j++)
            acc[i][j] = zero4();

    const int m = lane & 15;
    const int g8 = (lane >> 4) * 8;   // byte offset of 4-elem k-group within row

    for (int k0 = 0; k0 < K; k0 += 64) {
        // stage 128x64 A-tile + 128x64 Bt-tile (128 B per row)
        #pragma unroll
        for (int i = 0; i < 4; i++) {
            const int r = (w * 4 + i) * 8 + (lane >> 3);
            const int sc = (lane & 7) ^ (r & 7);       // 16B-chunk swizzle
            GLOAD_LDS16(A + (size_t)(tileM + r) * K + k0 + sc * 8,
                        (char*)As + (w * 4 + i) * 1024);
            GLOAD_LDS16(Bt + (size_t)(tileN + r) * K + k0 + sc * 8,
                        (char*)Bs + (w * 4 + i) * 1024);
        }
        __syncthreads();

        FragAB af[4][2], bfb[4][2];
        #pragma unroll
        for (int mi = 0; mi < 4; mi++) {
            const int ar = (w >> 1) * 64 + mi * 16 + m;
            const char* rp = (const char*)As + ar * 128;
            const int sw = (ar & 7) << 4;
            #pragma unroll
            for (int ks = 0; ks < 2; ks++) {
                af[mi][ks].q[0] = *(const u32x2*)(rp + ((ks * 64 + g8) ^ sw));
                af[mi][ks].q[1] = *(const u32x2*)(rp + ((ks * 64 + 32 + g8) ^ sw));
            }
        }
        #pragma unroll
        for (int ni = 0; ni < 4; ni++) {
            const int br = (w & 1) * 64 + ni * 16 + m;
            const char* rp = (const char*)Bs + br * 128;
            const int sw = (br & 7) << 4;
            #pragma unroll
            for (int ks = 0; ks < 2; ks++) {
                bfb[ni][ks].q[0] = *(const u32x2*)(rp + ((ks * 64 + g8) ^ sw));
                bfb[ni][ks].q[1] = *(const u32x2*)(rp + ((ks * 64 + 32 + g8) ^ sw));
            }
        }
        #pragma unroll
        for (int ks = 0; ks < 2; ks++)
            #pragma unroll
            for (int mi = 0; mi < 4; mi++)
                #pragma unroll
                for (int ni = 0; ni < 4; ni++)
                    acc[mi][ni] = __builtin_amdgcn_mfma_f32_16x16x32_bf16(
                        af[mi][ks].v, bfb[ni][ks].v, acc[mi][ni], 0, 0, 0);
        __syncthreads();
    }

    // epilogue: D layout col=lane&15, row=(lane>>4)*4+reg  [verified m89]
    #pragma unroll
    for (int mi = 0; mi < 4; mi++) {
        #pragma unroll
        for (int ni = 0; ni < 4; ni++) {
            #pragma unroll
            for (int r = 0; r < 4; r++) {
                const int grow = tileM + (w >> 1) * 64 + mi * 16 + (lane >> 4) * 4 + r;
                const int gcol = tileN + (w & 1) * 64 + ni * 16 + (lane & 15);
                float v = acc[mi][ni][r];
                if (HAS_BIAS) v += bias[gcol];
                if (HAS_RES) v += res[(size_t)grow * N + gcol];
                if (RELU) v = fmaxf(v, 0.f);
                const size_t o = (size_t)grow * N + gcol;
                if (OUT_BF16) ((u16*)Out)[o] = f2bf(v);
                else ((float*)Out)[o] = v;
            }
        }
    }
}

// ---------------------------------------------------------------- attention
// one block per (local batch, head). qkv: [rows][1152] bf16 chunk (q|k|v per head),
// out: full [32768][384] bf16 base, rows offset by row0.
__global__ __launch_bounds__(256) void attn_kernel(
        const u16* __restrict__ qkv, u16* __restrict__ out, int row0)
{
    __shared__ u16 Kl[256 * 72];       // K rows, +8 pad
    __shared__ u16 Vt[64 * 264];       // V transposed [d][s], +8 pad
    __shared__ u16 Pl[4 * 16 * 264];   // per-wave P tile [16][256], +8 pad

    const int bi = blockIdx.x / 6, h = blockIdx.x % 6;
    const int tid = threadIdx.x, lane = tid & 63, w = tid >> 6;
    const u16* base = qkv + (size_t)bi * 256 * 1152 + h * 64;

    // stage K rows and V^T; each thread covers 8 bf16 = 16 B (u32x4)
    #pragma unroll
    for (int pass = 0; pass < 8; pass++) {
        const int s = pass * 32 + (tid >> 3);
        const int d8 = (tid & 7) * 8;
        const u16* krow = base + (size_t)s * 1152;
        *(u32x4*)(&Kl[s * 72 + d8]) = *(const u32x4*)(krow + 384 + d8);
        Stage16 vv;
        vv.v = *(const u32x4*)(krow + 768 + d8);
        #pragma unroll
        for (int j = 0; j < 8; j++) Vt[(d8 + j) * 264 + s] = vv.e[j];
    }
    __syncthreads();

    const int m = lane & 15;
    const int g4 = (lane >> 4) * 4;
    u16* pw = &Pl[w * 16 * 264];

    for (int p = 0; p < 4; p++) {
        const int rt = p * 4 + w;     // row-tile 0..15
        const int rp = rt * 16;
        const int nt = rt + 1;        // causal: col-tiles needed

        FragAB qa[2];
        const u16* qrow = base + (size_t)(rp + m) * 1152;
        #pragma unroll
        for (int ks = 0; ks < 2; ks++) {
            qa[ks].q[0] = *(const u32x2*)(qrow + ks * 32 + g4);
            qa[ks].q[1] = *(const u32x2*)(qrow + ks * 32 + 16 + g4);
        }

        f32x4_t sacc[16];
        #pragma unroll
        for (int ct = 0; ct < 16; ct++) {
            if (ct < nt) {
                sacc[ct] = zero4();
                #pragma unroll
                for (int ks = 0; ks < 2; ks++) {
                    FragAB kb;
                    const u16* kr = &Kl[(ct * 16 + m) * 72 + ks * 32 + g4];
                    kb.q[0] = *(const u32x2*)(kr);
                    kb.q[1] = *(const u32x2*)(kr + 16);
                    sacc[ct] = __builtin_amdgcn_mfma_f32_16x16x32_bf16(
                        qa[ks].v, kb.v, sacc[ct], 0, 0, 0);
                }
            }
        }

        const int rbase = rp + (lane >> 4) * 4;
        float mx[4] = {-1e30f, -1e30f, -1e30f, -1e30f};
        #pragma unroll
        for (int ct = 0; ct < 16; ct++) if (ct < nt) {
            #pragma unroll
            for (int r = 0; r < 4; r++) {
                float v = sacc[ct][r] * SCALE_QK;
                if (ct * 16 + m > rbase + r) v = NEG_BIG;
                sacc[ct][r] = v;
                mx[r] = fmaxf(mx[r], v);
            }
        }
        #pragma unroll
        for (int r = 0; r < 4; r++) {
            #pragma unroll
            for (int o = 1; o < 16; o <<= 1) mx[r] = fmaxf(mx[r], __shfl_xor(mx[r], o));
        }
        float sum[4] = {0.f, 0.f, 0.f, 0.f};
        #pragma unroll
        for (int ct = 0; ct < 16; ct++) if (ct < nt) {
            #pragma unroll
            for (int r = 0; r < 4; r++) {
                const float e = __expf(sacc[ct][r] - mx[r]);
                sacc[ct][r] = e;
                sum[r] += e;
            }
        }
        #pragma unroll
        for (int r = 0; r < 4; r++) {
            #pragma unroll
            for (int o = 1; o < 16; o <<= 1) sum[r] += __shfl_xor(sum[r], o);
        }
        float inv[4];
        #pragma unroll
        for (int r = 0; r < 4; r++) inv[r] = 1.f / sum[r];

        #pragma unroll
        for (int ct = 0; ct < 16; ct++) if (ct < nt) {
            #pragma unroll
            for (int r = 0; r < 4; r++)
                pw[((lane >> 4) * 4 + r) * 264 + ct * 16 + m] = f2bf(sacc[ct][r] * inv[r]);
        }
        if (nt & 1) {
            #pragma unroll
            for (int r = 0; r < 4; r++)
                pw[((lane >> 4) * 4 + r) * 264 + nt * 16 + m] = 0;
        }

        const int kpairs = (nt + 1) >> 1;
        f32x4_t oacc[4];
        #pragma unroll
        for (int ni = 0; ni < 4; ni++) oacc[ni] = zero4();
        #pragma unroll
        for (int kk = 0; kk < 8; kk++) if (kk < kpairs) {
            FragAB pa;
            const u16* pr = &pw[m * 264 + kk * 32 + g4];
            pa.q[0] = *(const u32x2*)(pr);
            pa.q[1] = *(const u32x2*)(pr + 16);
            #pragma unroll
            for (int ni = 0; ni < 4; ni++) {
                FragAB vb;
                const u16* vr = &Vt[(ni * 16 + m) * 264 + kk * 32 + g4];
                vb.q[0] = *(const u32x2*)(vr);
                vb.q[1] = *(const u32x2*)(vr + 16);
                oacc[ni] = __builtin_amdgcn_mfma_f32_16x16x32_bf16(
                    pa.v, vb.v, oacc[ni], 0, 0, 0);
            }
        }

        #pragma unroll
        for (int ni = 0; ni < 4; ni++) {
            #pragma unroll
            for (int r = 0; r < 4; r++) {
                const int t = rp + (lane >> 4) * 4 + r;
                out[((size_t)row0 + bi * 256 + t) * 384 + h * 64 + ni * 16 + m] =
                    f2bf(oacc[ni][r]);
            }
        }
    }
}

// ---------------------------------------------------------------- launch
extern "C" void kernel_launch(void* const* d_in, const int* in_sizes, int n_in,
                              void* d_out, int out_size, void* d_ws, size_t ws_size,
                              hipStream_t stream)
{
    (void)in_sizes; (void)n_in; (void)out_size;
    const float* x     = (const float*)d_in[0];
    const float* wq    = (const float*)d_in[1];
    const float* wk    = (const float*)d_in[2];
    const float* wv    = (const float*)d_in[3];
    const float* wproj = (const float*)d_in[4];
    const float* bproj = (const float*)d_in[5];
    const float* w1    = (const float*)d_in[6];
    const float* b1    = (const float*)d_in[7];
    const float* w2    = (const float*)d_in[8];
    const float* b2    = (const float*)d_in[9];
    const float* ln1g  = (const float*)d_in[10];
    const float* ln1b  = (const float*)d_in[11];
    const float* ln2g  = (const float*)d_in[12];
    const float* ln2b  = (const float*)d_in[13];
    float* out = (float*)d_out;

    // Fixed region: 28,704,768 B. Dynamic region holds qkv-chunk / mlp1-chunk.
    char* ws = (char*)d_ws;
    u16* hattn  = (u16*)(ws);                 // 25,165,824 B (LN1 out -> attn out -> LN2 out)
    u16* wqkvT  = (u16*)(ws + 25165824);      //    884,736 B
    u16* wprojT = (u16*)(ws + 26050560);      //    294,912 B
    u16* w1T    = (u16*)(ws + 26345472);      //  1,179,648 B
    u16* w2T    = (u16*)(ws + 27525120);      //  1,179,648 B
    char* dyn   = ws + 28704768;
    const size_t avail = (ws_size > (size_t)28704768) ? ws_size - (size_t)28704768 : (size_t)0;

    int na = 32, nm = 32;   // batch-chunk counts for qkv phase / mlp phase
    for (int n = 1; n <= 32; n <<= 1) if ((size_t)75497472  / n <= avail) { na = n; break; }
    for (int n = 1; n <= 32; n <<= 1) if ((size_t)100663296 / n <= avail) { nm = n; break; }

    qkv_w_kernel<<<1728, 256, 0, stream>>>(wq, wk, wv, wqkvT);
    transpose_w_kernel<<<576, 256, 0, stream>>>(wproj, wprojT, 384, 384);
    transpose_w_kernel<<<2304, 256, 0, stream>>>(w1, w1T, 384, 1536);
    transpose_w_kernel<<<2304, 256, 0, stream>>>(w2, w2T, 1536, 384);

    // LN1: x -> h (bf16)
    ln_kernel<<<8192, 256, 0, stream>>>(x, ln1g, ln1b, hattn);

    // QKV gemm + attention, chunked over batches; attn overlays h rows already consumed
    const int rows_a = 32768 / na, bat_a = 128 / na;
    u16* qkvc = (u16*)dyn;
    for (int c = 0; c < na; c++) {
        const int row0 = c * rows_a;
        gemm_kernel<false, false, false, true><<<dim3(9, rows_a / 128), 256, 0, stream>>>(
            hattn + (size_t)row0 * 384, wqkvT, nullptr, nullptr, qkvc, rows_a, 1152, 384);
        attn_kernel<<<bat_a * 6, 256, 0, stream>>>(qkvc, hattn, row0);
    }

    // proj + bias + residual(x) -> out (fp32)
    gemm_kernel<true, true, false, false><<<dim3(3, 256), 256, 0, stream>>>(
        hattn, wprojT, bproj, x, out, 32768, 384, 384);

    // LN2: out -> h (bf16)
    ln_kernel<<<8192, 256, 0, stream>>>(out, ln2g, ln2b, hattn);

    // MLP, chunked: fc1(+bias,relu) -> mlp1 chunk; fc2(+bias,+residual) -> out
    const int rows_m = 32768 / nm;
    u16* mlp1c = (u16*)dyn;
    for (int c = 0; c < nm; c++) {
        const int row0 = c * rows_m;
        gemm_kernel<true, false, true, true><<<dim3(12, rows_m / 128), 256, 0, stream>>>(
            hattn + (size_t)row0 * 384, w1T, b1, nullptr, mlp1c, rows_m, 1536, 384);
        gemm_kernel<true, true, false, false><<<dim3(3, rows_m / 128), 256, 0, stream>>>(
            mlp1c, w2T, b2, out + (size_t)row0 * 384, out + (size_t)row0 * 384,
            rows_m, 384, 1536);
    }
}

// Round 6
// 453.138 us; speedup vs baseline: 1.0440x; 1.0120x over previous
//
#include <hip/hip_runtime.h>
#include <stdint.h>

typedef unsigned short u16;
typedef unsigned int u32;
typedef __bf16 bf16x8_t __attribute__((ext_vector_type(8)));
typedef float f32x4_t __attribute__((ext_vector_type(4)));
typedef unsigned int u32x2 __attribute__((ext_vector_type(2)));
typedef unsigned int u32x4 __attribute__((ext_vector_type(4)));

union FragAB { bf16x8_t v; u32x2 q[2]; };   // attention (b64-pair layout)
union Frag128 { bf16x8_t v; u32x4 q; };     // GEMM (contiguous b128 layout)
union Stage16 { u32x4 v; u16 e[8]; };

#define DEVFN static __device__ __forceinline__

DEVFN u16 f2bf(float f) {
    u32 x = __builtin_bit_cast(u32, f);
    return (u16)((x + 0x7fffu + ((x >> 16) & 1u)) >> 16);
}

DEVFN f32x4_t zero4() { f32x4_t z = {0.f, 0.f, 0.f, 0.f}; return z; }

typedef __attribute__((address_space(1))) void as1_void;
typedef __attribute__((address_space(3))) void as3_void;

#define GLOAD_LDS16(src, dst) \
    __builtin_amdgcn_global_load_lds((as1_void*)(void*)(src), (as3_void*)(dst), 16, 0, 0)

// B=128, T=256, C=384, H=6, D=64; rows = B*T = 32768
#define SCALE_QK 0.051031036307982884f  /* 1/sqrt(384) */
#define NEG_BIG  -30000.0f

// ---------------------------------------------------------------- LayerNorm
__global__ __launch_bounds__(256) void ln_kernel(
        const float* __restrict__ in, const float* __restrict__ g,
        const float* __restrict__ b, u16* __restrict__ out)
{
    const int lane = threadIdx.x & 63;
    const int w = threadIdx.x >> 6;
    const int row = blockIdx.x * 4 + w;
    const float* rp = in + (size_t)row * 384;
    float v[6];
    float s = 0.f, sq = 0.f;
    #pragma unroll
    for (int j = 0; j < 6; j++) {
        v[j] = rp[lane + j * 64];
        s += v[j];
        sq += v[j] * v[j];
    }
    #pragma unroll
    for (int o = 32; o >= 1; o >>= 1) {
        s  += __shfl_xor(s, o);
        sq += __shfl_xor(sq, o);
    }
    const float mean = s * (1.f / 384.f);
    const float var = sq * (1.f / 384.f) - mean * mean;
    const float rs = rsqrtf(var + 1e-5f);
    u16* op = out + (size_t)row * 384;
    #pragma unroll
    for (int j = 0; j < 6; j++) {
        const int c = lane + j * 64;
        op[c] = f2bf((v[j] - mean) * rs * g[c] + b[c]);
    }
}

// ------------------------------------------------------- weight repack (bf16)
__global__ void qkv_w_kernel(const float* __restrict__ wq, const float* __restrict__ wk,
                             const float* __restrict__ wv, u16* __restrict__ bt)
{
    const int idx = blockIdx.x * 256 + threadIdx.x;
    if (idx >= 1152 * 384) return;
    const int j = idx / 384, c = idx % 384;
    const int which = j / 384;
    const int r = j % 384;
    const int h = r / 64, d = r % 64;
    const float* w = (which == 0) ? wq : (which == 1 ? wk : wv);
    bt[idx] = f2bf(w[(h * 384 + c) * 64 + d]);
}

__global__ void transpose_w_kernel(const float* __restrict__ w, u16* __restrict__ bt,
                                   int K, int N)
{
    const int idx = blockIdx.x * 256 + threadIdx.x;
    if (idx >= K * N) return;
    const int n = idx / K, k = idx % K;
    bt[idx] = f2bf(w[(size_t)k * N + n]);
}

// ---------------------------------------------------------------- GEMM
// C[M][N] = A[M][K] * Bt[N][K]^T  (+bias, +res, relu, bf16/f32 out)
// 128x128 tile, BK=64, 4 waves of 64x64.
// global_load_lds width-16 staging: linear LDS dest, source 16B-chunk index
// pre-XORed with (row&7); fragment reads are single ds_read_b128 with the
// same XOR (contiguous k = (lane>>4)*8+0..7, identical for A and B).
template<bool HAS_BIAS, bool HAS_RES, bool RELU, bool OUT_BF16>
__global__ __launch_bounds__(256) void gemm_kernel(
        const u16* __restrict__ A, const u16* __restrict__ Bt,
        const float* __restrict__ bias, const float* __restrict__ res,
        void* __restrict__ Out, int M, int N, int K)
{
    __shared__ u16 As[128 * 64];
    __shared__ u16 Bs[128 * 64];
    const int tid = threadIdx.x;
    const int lane = tid & 63;
    const int w = tid >> 6;
    const int tileN = blockIdx.x * 128;
    const int tileM = blockIdx.y * 128;
    (void)M;

    f32x4_t acc[4][4];
    #pragma unroll
    for (int i = 0; i < 4; i++)
        #pragma unroll
        for (int j = 0; j < 4; j++)
            acc[i][j] = zero4();

    const int m = lane & 15;
    const int g16 = (lane >> 4) * 16;   // byte offset of contiguous 8-elem k-group

    for (int k0 = 0; k0 < K; k0 += 64) {
        // stage 128x64 A-tile + 128x64 Bt-tile (128 B per row)
        #pragma unroll
        for (int i = 0; i < 4; i++) {
            const int r = (w * 4 + i) * 8 + (lane >> 3);
            const int sc = (lane & 7) ^ (r & 7);       // 16B-chunk swizzle
            GLOAD_LDS16(A + (size_t)(tileM + r) * K + k0 + sc * 8,
                        (char*)As + (w * 4 + i) * 1024);
            GLOAD_LDS16(Bt + (size_t)(tileN + r) * K + k0 + sc * 8,
                        (char*)Bs + (w * 4 + i) * 1024);
        }
        __syncthreads();

        Frag128 af[4][2], bfb[4][2];
        #pragma unroll
        for (int mi = 0; mi < 4; mi++) {
            const int ar = (w >> 1) * 64 + mi * 16 + m;
            const char* rp = (const char*)As + ar * 128;
            const int sw = (ar & 7) << 4;
            #pragma unroll
            for (int ks = 0; ks < 2; ks++)
                af[mi][ks].q = *(const u32x4*)(rp + ((ks * 64 + g16) ^ sw));
        }
        #pragma unroll
        for (int ni = 0; ni < 4; ni++) {
            const int br = (w & 1) * 64 + ni * 16 + m;
            const char* rp = (const char*)Bs + br * 128;
            const int sw = (br & 7) << 4;
            #pragma unroll
            for (int ks = 0; ks < 2; ks++)
                bfb[ni][ks].q = *(const u32x4*)(rp + ((ks * 64 + g16) ^ sw));
        }
        #pragma unroll
        for (int ks = 0; ks < 2; ks++)
            #pragma unroll
            for (int mi = 0; mi < 4; mi++)
                #pragma unroll
                for (int ni = 0; ni < 4; ni++)
                    acc[mi][ni] = __builtin_amdgcn_mfma_f32_16x16x32_bf16(
                        af[mi][ks].v, bfb[ni][ks].v, acc[mi][ni], 0, 0, 0);
        __syncthreads();
    }

    // epilogue: D layout col=lane&15, row=(lane>>4)*4+reg  [verified m89]
    #pragma unroll
    for (int mi = 0; mi < 4; mi++) {
        #pragma unroll
        for (int ni = 0; ni < 4; ni++) {
            #pragma unroll
            for (int r = 0; r < 4; r++) {
                const int grow = tileM + (w >> 1) * 64 + mi * 16 + (lane >> 4) * 4 + r;
                const int gcol = tileN + (w & 1) * 64 + ni * 16 + (lane & 15);
                float v = acc[mi][ni][r];
                if (HAS_BIAS) v += bias[gcol];
                if (HAS_RES) v += res[(size_t)grow * N + gcol];
                if (RELU) v = fmaxf(v, 0.f);
                const size_t o = (size_t)grow * N + gcol;
                if (OUT_BF16) ((u16*)Out)[o] = f2bf(v);
                else ((float*)Out)[o] = v;
            }
        }
    }
}

// ---------------------------------------------------------------- attention
// one block per (local batch, head). qkv: [rows][1152] bf16 chunk (q|k|v per head),
// out: full [32768][384] bf16 base, rows offset by row0.
__global__ __launch_bounds__(256) void attn_kernel(
        const u16* __restrict__ qkv, u16* __restrict__ out, int row0)
{
    __shared__ u16 Kl[256 * 72];       // K rows, +8 pad
    __shared__ u16 Vt[64 * 264];       // V transposed [d][s], +8 pad
    __shared__ u16 Pl[4 * 16 * 264];   // per-wave P tile [16][256], +8 pad

    const int bi = blockIdx.x / 6, h = blockIdx.x % 6;
    const int tid = threadIdx.x, lane = tid & 63, w = tid >> 6;
    const u16* base = qkv + (size_t)bi * 256 * 1152 + h * 64;

    // stage K rows and V^T; each thread covers 8 bf16 = 16 B (u32x4)
    #pragma unroll
    for (int pass = 0; pass < 8; pass++) {
        const int s = pass * 32 + (tid >> 3);
        const int d8 = (tid & 7) * 8;
        const u16* krow = base + (size_t)s * 1152;
        *(u32x4*)(&Kl[s * 72 + d8]) = *(const u32x4*)(krow + 384 + d8);
        Stage16 vv;
        vv.v = *(const u32x4*)(krow + 768 + d8);
        #pragma unroll
        for (int j = 0; j < 8; j++) Vt[(d8 + j) * 264 + s] = vv.e[j];
    }
    __syncthreads();

    const int m = lane & 15;
    const int g4 = (lane >> 4) * 4;
    u16* pw = &Pl[w * 16 * 264];

    for (int p = 0; p < 4; p++) {
        const int rt = p * 4 + w;     // row-tile 0..15
        const int rp = rt * 16;
        const int nt = rt + 1;        // causal: col-tiles needed

        FragAB qa[2];
        const u16* qrow = base + (size_t)(rp + m) * 1152;
        #pragma unroll
        for (int ks = 0; ks < 2; ks++) {
            qa[ks].q[0] = *(const u32x2*)(qrow + ks * 32 + g4);
            qa[ks].q[1] = *(const u32x2*)(qrow + ks * 32 + 16 + g4);
        }

        f32x4_t sacc[16];
        #pragma unroll
        for (int ct = 0; ct < 16; ct++) {
            if (ct < nt) {
                sacc[ct] = zero4();
                #pragma unroll
                for (int ks = 0; ks < 2; ks++) {
                    FragAB kb;
                    const u16* kr = &Kl[(ct * 16 + m) * 72 + ks * 32 + g4];
                    kb.q[0] = *(const u32x2*)(kr);
                    kb.q[1] = *(const u32x2*)(kr + 16);
                    sacc[ct] = __builtin_amdgcn_mfma_f32_16x16x32_bf16(
                        qa[ks].v, kb.v, sacc[ct], 0, 0, 0);
                }
            }
        }

        const int rbase = rp + (lane >> 4) * 4;
        float mx[4] = {-1e30f, -1e30f, -1e30f, -1e30f};
        #pragma unroll
        for (int ct = 0; ct < 16; ct++) if (ct < nt) {
            #pragma unroll
            for (int r = 0; r < 4; r++) {
                float v = sacc[ct][r] * SCALE_QK;
                if (ct * 16 + m > rbase + r) v = NEG_BIG;
                sacc[ct][r] = v;
                mx[r] = fmaxf(mx[r], v);
            }
        }
        #pragma unroll
        for (int r = 0; r < 4; r++) {
            #pragma unroll
            for (int o = 1; o < 16; o <<= 1) mx[r] = fmaxf(mx[r], __shfl_xor(mx[r], o));
        }
        float sum[4] = {0.f, 0.f, 0.f, 0.f};
        #pragma unroll
        for (int ct = 0; ct < 16; ct++) if (ct < nt) {
            #pragma unroll
            for (int r = 0; r < 4; r++) {
                const float e = __expf(sacc[ct][r] - mx[r]);
                sacc[ct][r] = e;
                sum[r] += e;
            }
        }
        #pragma unroll
        for (int r = 0; r < 4; r++) {
            #pragma unroll
            for (int o = 1; o < 16; o <<= 1) sum[r] += __shfl_xor(sum[r], o);
        }
        float inv[4];
        #pragma unroll
        for (int r = 0; r < 4; r++) inv[r] = 1.f / sum[r];

        #pragma unroll
        for (int ct = 0; ct < 16; ct++) if (ct < nt) {
            #pragma unroll
            for (int r = 0; r < 4; r++)
                pw[((lane >> 4) * 4 + r) * 264 + ct * 16 + m] = f2bf(sacc[ct][r] * inv[r]);
        }
        if (nt & 1) {
            #pragma unroll
            for (int r = 0; r < 4; r++)
                pw[((lane >> 4) * 4 + r) * 264 + nt * 16 + m] = 0;
        }

        const int kpairs = (nt + 1) >> 1;
        f32x4_t oacc[4];
        #pragma unroll
        for (int ni = 0; ni < 4; ni++) oacc[ni] = zero4();
        #pragma unroll
        for (int kk = 0; kk < 8; kk++) if (kk < kpairs) {
            FragAB pa;
            const u16* pr = &pw[m * 264 + kk * 32 + g4];
            pa.q[0] = *(const u32x2*)(pr);
            pa.q[1] = *(const u32x2*)(pr + 16);
            #pragma unroll
            for (int ni = 0; ni < 4; ni++) {
                FragAB vb;
                const u16* vr = &Vt[(ni * 16 + m) * 264 + kk * 32 + g4];
                vb.q[0] = *(const u32x2*)(vr);
                vb.q[1] = *(const u32x2*)(vr + 16);
                oacc[ni] = __builtin_amdgcn_mfma_f32_16x16x32_bf16(
                    pa.v, vb.v, oacc[ni], 0, 0, 0);
            }
        }

        #pragma unroll
        for (int ni = 0; ni < 4; ni++) {
            #pragma unroll
            for (int r = 0; r < 4; r++) {
                const int t = rp + (lane >> 4) * 4 + r;
                out[((size_t)row0 + bi * 256 + t) * 384 + h * 64 + ni * 16 + m] =
                    f2bf(oacc[ni][r]);
            }
        }
    }
}

// ---------------------------------------------------------------- launch
extern "C" void kernel_launch(void* const* d_in, const int* in_sizes, int n_in,
                              void* d_out, int out_size, void* d_ws, size_t ws_size,
                              hipStream_t stream)
{
    (void)in_sizes; (void)n_in; (void)out_size;
    const float* x     = (const float*)d_in[0];
    const float* wq    = (const float*)d_in[1];
    const float* wk    = (const float*)d_in[2];
    const float* wv    = (const float*)d_in[3];
    const float* wproj = (const float*)d_in[4];
    const float* bproj = (const float*)d_in[5];
    const float* w1    = (const float*)d_in[6];
    const float* b1    = (const float*)d_in[7];
    const float* w2    = (const float*)d_in[8];
    const float* b2    = (const float*)d_in[9];
    const float* ln1g  = (const float*)d_in[10];
    const float* ln1b  = (const float*)d_in[11];
    const float* ln2g  = (const float*)d_in[12];
    const float* ln2b  = (const float*)d_in[13];
    float* out = (float*)d_out;

    // Fixed region: 28,704,768 B. Dynamic region holds qkv-chunk / mlp1-chunk.
    char* ws = (char*)d_ws;
    u16* hattn  = (u16*)(ws);                 // 25,165,824 B (LN1 out -> attn out -> LN2 out)
    u16* wqkvT  = (u16*)(ws + 25165824);      //    884,736 B
    u16* wprojT = (u16*)(ws + 26050560);      //    294,912 B
    u16* w1T    = (u16*)(ws + 26345472);      //  1,179,648 B
    u16* w2T    = (u16*)(ws + 27525120);      //  1,179,648 B
    char* dyn   = ws + 28704768;
    const size_t avail = (ws_size > (size_t)28704768) ? ws_size - (size_t)28704768 : (size_t)0;

    int na = 32, nm = 32;   // batch-chunk counts for qkv phase / mlp phase
    for (int n = 1; n <= 32; n <<= 1) if ((size_t)75497472  / n <= avail) { na = n; break; }
    for (int n = 1; n <= 32; n <<= 1) if ((size_t)100663296 / n <= avail) { nm = n; break; }

    qkv_w_kernel<<<1728, 256, 0, stream>>>(wq, wk, wv, wqkvT);
    transpose_w_kernel<<<576, 256, 0, stream>>>(wproj, wprojT, 384, 384);
    transpose_w_kernel<<<2304, 256, 0, stream>>>(w1, w1T, 384, 1536);
    transpose_w_kernel<<<2304, 256, 0, stream>>>(w2, w2T, 1536, 384);

    // LN1: x -> h (bf16)
    ln_kernel<<<8192, 256, 0, stream>>>(x, ln1g, ln1b, hattn);

    // QKV gemm + attention, chunked over batches; attn overlays h rows already consumed
    const int rows_a = 32768 / na, bat_a = 128 / na;
    u16* qkvc = (u16*)dyn;
    for (int c = 0; c < na; c++) {
        const int row0 = c * rows_a;
        gemm_kernel<false, false, false, true><<<dim3(9, rows_a / 128), 256, 0, stream>>>(
            hattn + (size_t)row0 * 384, wqkvT, nullptr, nullptr, qkvc, rows_a, 1152, 384);
        attn_kernel<<<bat_a * 6, 256, 0, stream>>>(qkvc, hattn, row0);
    }

    // proj + bias + residual(x) -> out (fp32)
    gemm_kernel<true, true, false, false><<<dim3(3, 256), 256, 0, stream>>>(
        hattn, wprojT, bproj, x, out, 32768, 384, 384);

    // LN2: out -> h (bf16)
    ln_kernel<<<8192, 256, 0, stream>>>(out, ln2g, ln2b, hattn);

    // MLP, chunked: fc1(+bias,relu) -> mlp1 chunk; fc2(+bias,+residual) -> out
    const int rows_m = 32768 / nm;
    u16* mlp1c = (u16*)dyn;
    for (int c = 0; c < nm; c++) {
        const int row0 = c * rows_m;
        gemm_kernel<true, false, true, true><<<dim3(12, rows_m / 128), 256, 0, stream>>>(
            hattn + (size_t)row0 * 384, w1T, b1, nullptr, mlp1c, rows_m, 1536, 384);
        gemm_kernel<true, true, false, false><<<dim3(3, rows_m / 128), 256, 0, stream>>>(
            mlp1c, w2T, b2, out + (size_t)row0 * 384, out + (size_t)row0 * 384,
            rows_m, 384, 1536);
    }
}

// Round 7
// 445.727 us; speedup vs baseline: 1.0614x; 1.0166x over previous
//
#include <hip/hip_runtime.h>
#include <stdint.h>

typedef unsigned short u16;
typedef unsigned int u32;
typedef __bf16 bf16x8_t __attribute__((ext_vector_type(8)));
typedef float f32x4_t __attribute__((ext_vector_type(4)));
typedef unsigned int u32x2 __attribute__((ext_vector_type(2)));
typedef unsigned int u32x4 __attribute__((ext_vector_type(4)));

union FragAB { bf16x8_t v; u32x2 q[2]; };   // b64-pair k-layout (PV path)
union Frag128 { bf16x8_t v; u32x4 q; };     // contiguous b128 k-layout
union Stage16 { u32x4 v; u16 e[8]; };

#define DEVFN static __device__ __forceinline__

DEVFN u16 f2bf(float f) {
    u32 x = __builtin_bit_cast(u32, f);
    return (u16)((x + 0x7fffu + ((x >> 16) & 1u)) >> 16);
}

DEVFN u32 pack2bf(float a, float b) {
    return (u32)f2bf(a) | ((u32)f2bf(b) << 16);
}

DEVFN f32x4_t zero4() { f32x4_t z = {0.f, 0.f, 0.f, 0.f}; return z; }

typedef __attribute__((address_space(1))) void as1_void;
typedef __attribute__((address_space(3))) void as3_void;

#define GLOAD_LDS16(src, dst) \
    __builtin_amdgcn_global_load_lds((as1_void*)(void*)(src), (as3_void*)(dst), 16, 0, 0)

// B=128, T=256, C=384, H=6, D=64; rows = B*T = 32768
#define SCALE_QK 0.051031036307982884f  /* 1/sqrt(384) */
#define NEG_BIG  -30000.0f

// ---------------------------------------------------------------- LayerNorm
__global__ __launch_bounds__(256) void ln_kernel(
        const float* __restrict__ in, const float* __restrict__ g,
        const float* __restrict__ b, u16* __restrict__ out)
{
    const int lane = threadIdx.x & 63;
    const int w = threadIdx.x >> 6;
    const int row = blockIdx.x * 4 + w;
    const float* rp = in + (size_t)row * 384;
    float v[6];
    float s = 0.f, sq = 0.f;
    #pragma unroll
    for (int j = 0; j < 6; j++) {
        v[j] = rp[lane + j * 64];
        s += v[j];
        sq += v[j] * v[j];
    }
    #pragma unroll
    for (int o = 32; o >= 1; o >>= 1) {
        s  += __shfl_xor(s, o);
        sq += __shfl_xor(sq, o);
    }
    const float mean = s * (1.f / 384.f);
    const float var = sq * (1.f / 384.f) - mean * mean;
    const float rs = rsqrtf(var + 1e-5f);
    u16* op = out + (size_t)row * 384;
    #pragma unroll
    for (int j = 0; j < 6; j++) {
        const int c = lane + j * 64;
        op[c] = f2bf((v[j] - mean) * rs * g[c] + b[c]);
    }
}

// ------------------------------------------------------- weight repack (bf16)
__global__ void qkv_w_kernel(const float* __restrict__ wq, const float* __restrict__ wk,
                             const float* __restrict__ wv, u16* __restrict__ bt)
{
    const int idx = blockIdx.x * 256 + threadIdx.x;
    if (idx >= 1152 * 384) return;
    const int j = idx / 384, c = idx % 384;
    const int which = j / 384;
    const int r = j % 384;
    const int h = r / 64, d = r % 64;
    const float* w = (which == 0) ? wq : (which == 1 ? wk : wv);
    bt[idx] = f2bf(w[(h * 384 + c) * 64 + d]);
}

__global__ void transpose_w_kernel(const float* __restrict__ w, u16* __restrict__ bt,
                                   int K, int N)
{
    const int idx = blockIdx.x * 256 + threadIdx.x;
    if (idx >= K * N) return;
    const int n = idx / K, k = idx % K;
    bt[idx] = f2bf(w[(size_t)k * N + n]);
}

// ---------------------------------------------------------------- GEMM
// C[M][N] = A[M][K] * Bt[N][K]^T  (+bias, +res, relu, bf16/f32 out)
// 128x128 tile, BK=64, 4 waves of 64x64.
// global_load_lds width-16 staging: linear LDS dest, source 16B-chunk index
// pre-XORed with (row&7); fragment reads are single ds_read_b128 with the
// same XOR (contiguous k = (lane>>4)*8+0..7, identical for A and B).
template<bool HAS_BIAS, bool HAS_RES, bool RELU, bool OUT_BF16>
__global__ __launch_bounds__(256) void gemm_kernel(
        const u16* __restrict__ A, const u16* __restrict__ Bt,
        const float* __restrict__ bias, const float* __restrict__ res,
        void* __restrict__ Out, int M, int N, int K)
{
    __shared__ u16 As[128 * 64];
    __shared__ u16 Bs[128 * 64];
    const int tid = threadIdx.x;
    const int lane = tid & 63;
    const int w = tid >> 6;
    const int tileN = blockIdx.x * 128;
    const int tileM = blockIdx.y * 128;
    (void)M;

    f32x4_t acc[4][4];
    #pragma unroll
    for (int i = 0; i < 4; i++)
        #pragma unroll
        for (int j = 0; j < 4; j++)
            acc[i][j] = zero4();

    const int m = lane & 15;
    const int g16 = (lane >> 4) * 16;   // byte offset of contiguous 8-elem k-group

    for (int k0 = 0; k0 < K; k0 += 64) {
        // stage 128x64 A-tile + 128x64 Bt-tile (128 B per row)
        #pragma unroll
        for (int i = 0; i < 4; i++) {
            const int r = (w * 4 + i) * 8 + (lane >> 3);
            const int sc = (lane & 7) ^ (r & 7);       // 16B-chunk swizzle
            GLOAD_LDS16(A + (size_t)(tileM + r) * K + k0 + sc * 8,
                        (char*)As + (w * 4 + i) * 1024);
            GLOAD_LDS16(Bt + (size_t)(tileN + r) * K + k0 + sc * 8,
                        (char*)Bs + (w * 4 + i) * 1024);
        }
        __syncthreads();

        Frag128 af[4][2], bfb[4][2];
        #pragma unroll
        for (int mi = 0; mi < 4; mi++) {
            const int ar = (w >> 1) * 64 + mi * 16 + m;
            const char* rp = (const char*)As + ar * 128;
            const int sw = (ar & 7) << 4;
            #pragma unroll
            for (int ks = 0; ks < 2; ks++)
                af[mi][ks].q = *(const u32x4*)(rp + ((ks * 64 + g16) ^ sw));
        }
        #pragma unroll
        for (int ni = 0; ni < 4; ni++) {
            const int br = (w & 1) * 64 + ni * 16 + m;
            const char* rp = (const char*)Bs + br * 128;
            const int sw = (br & 7) << 4;
            #pragma unroll
            for (int ks = 0; ks < 2; ks++)
                bfb[ni][ks].q = *(const u32x4*)(rp + ((ks * 64 + g16) ^ sw));
        }
        #pragma unroll
        for (int ks = 0; ks < 2; ks++)
            #pragma unroll
            for (int mi = 0; mi < 4; mi++)
                #pragma unroll
                for (int ni = 0; ni < 4; ni++)
                    acc[mi][ni] = __builtin_amdgcn_mfma_f32_16x16x32_bf16(
                        af[mi][ks].v, bfb[ni][ks].v, acc[mi][ni], 0, 0, 0);
        __syncthreads();
    }

    // epilogue: D layout col=lane&15, row=(lane>>4)*4+reg  [verified m89]
    #pragma unroll
    for (int mi = 0; mi < 4; mi++) {
        #pragma unroll
        for (int ni = 0; ni < 4; ni++) {
            #pragma unroll
            for (int r = 0; r < 4; r++) {
                const int grow = tileM + (w >> 1) * 64 + mi * 16 + (lane >> 4) * 4 + r;
                const int gcol = tileN + (w & 1) * 64 + ni * 16 + (lane & 15);
                float v = acc[mi][ni][r];
                if (HAS_BIAS) v += bias[gcol];
                if (HAS_RES) v += res[(size_t)grow * N + gcol];
                if (RELU) v = fmaxf(v, 0.f);
                const size_t o = (size_t)grow * N + gcol;
                if (OUT_BF16) ((u16*)Out)[o] = f2bf(v);
                else ((float*)Out)[o] = v;
            }
        }
    }
}

// ---------------------------------------------------------------- attention
// one block per (local batch, head). qkv: [rows][1152] bf16 chunk (q|k|v per head),
// out: full [32768][384] bf16 base, rows offset by row0.
// Swapped QK^T: S^T = mfma(K, Q) puts a full q-row's k-values lane-local
// (q = lane&15, k = ct*16 + (lane>>4)*4 + r) -> softmax is 2 shfl_xor and
// normalized P packs directly into the PV A-fragment. No P LDS buffer.
__global__ __launch_bounds__(256) void attn_kernel(
        const u16* __restrict__ qkv, u16* __restrict__ out, int row0)
{
    __shared__ u16 Kl[256 * 72];       // K rows [s][d], +8 pad (36,864 B)
    __shared__ u16 Vt[64 * 264];       // V transposed [d][s], +8 pad (33,792 B)

    const int bi = blockIdx.x / 6, h = blockIdx.x % 6;
    const int tid = threadIdx.x, lane = tid & 63, w = tid >> 6;
    const u16* base = qkv + (size_t)bi * 256 * 1152 + h * 64;

    // stage K rows and V^T; each thread covers 8 bf16 = 16 B (u32x4)
    #pragma unroll
    for (int pass = 0; pass < 8; pass++) {
        const int s = pass * 32 + (tid >> 3);
        const int d8 = (tid & 7) * 8;
        const u16* krow = base + (size_t)s * 1152;
        *(u32x4*)(&Kl[s * 72 + d8]) = *(const u32x4*)(krow + 384 + d8);
        Stage16 vv;
        vv.v = *(const u32x4*)(krow + 768 + d8);
        #pragma unroll
        for (int j = 0; j < 8; j++) Vt[(d8 + j) * 264 + s] = vv.e[j];
    }
    __syncthreads();

    const int m = lane & 15;            // q index within row-tile (QK^T), d index (PV)
    const int g4 = (lane >> 4) * 4;     // k-subgroup element offset (b64-pair perm)
    const int g8e = (lane >> 4) * 8;    // contiguous k-group (elements) for d-axis

    for (int p = 0; p < 4; p++) {
        const int rt = p * 4 + w;       // row-tile 0..15
        const int rp = rt * 16;
        const int nt = rt + 1;          // causal: col-tiles needed
        const int qg = rp + m;          // this lane's query row

        // Q fragment (B-operand): row rp+m, d-contiguous 8 elems per reg group
        Frag128 qb[2];
        const u16* qrow = base + (size_t)qg * 1152;
        #pragma unroll
        for (int ks = 0; ks < 2; ks++)
            qb[ks].q = *(const u32x4*)(qrow + ks * 32 + g8e);

        // S^T tiles: sacc[ct] lane layout: q = m, k = ct*16 + g4 + r
        f32x4_t sacc[16];
        #pragma unroll
        for (int ct = 0; ct < 16; ct++) {
            if (ct < nt) {
                sacc[ct] = zero4();
                #pragma unroll
                for (int ks = 0; ks < 2; ks++) {
                    Frag128 kb;
                    kb.q = *(const u32x4*)(&Kl[(ct * 16 + m) * 72 + ks * 32 + g8e]);
                    sacc[ct] = __builtin_amdgcn_mfma_f32_16x16x32_bf16(
                        kb.v, qb[ks].v, sacc[ct], 0, 0, 0);
                }
            }
        }

        // scale + causal mask; all 4*nt values belong to row qg
        float mx = -1e30f;
        #pragma unroll
        for (int ct = 0; ct < 16; ct++) if (ct < nt) {
            #pragma unroll
            for (int r = 0; r < 4; r++) {
                float v = sacc[ct][r] * SCALE_QK;
                if (ct * 16 + g4 + r > qg) v = NEG_BIG;
                sacc[ct][r] = v;
                mx = fmaxf(mx, v);
            }
        }
        mx = fmaxf(mx, __shfl_xor(mx, 16));
        mx = fmaxf(mx, __shfl_xor(mx, 32));

        float sum = 0.f;
        #pragma unroll
        for (int ct = 0; ct < 16; ct++) if (ct < nt) {
            #pragma unroll
            for (int r = 0; r < 4; r++) {
                const float e = __expf(sacc[ct][r] - mx);  // masked -> 0
                sacc[ct][r] = e;
                sum += e;
            }
        }
        sum += __shfl_xor(sum, 16);
        sum += __shfl_xor(sum, 32);
        const float inv = 1.f / sum;

        // O = P V; P fragments built in-register from sacc
        const int kpairs = (nt + 1) >> 1;
        f32x4_t oacc[4];
        #pragma unroll
        for (int ni = 0; ni < 4; ni++) oacc[ni] = zero4();
        #pragma unroll
        for (int kk = 0; kk < 8; kk++) if (kk < kpairs) {
            FragAB pa;
            {
                const f32x4_t p0 = sacc[2 * kk];
                pa.q[0][0] = pack2bf(p0[0] * inv, p0[1] * inv);
                pa.q[0][1] = pack2bf(p0[2] * inv, p0[3] * inv);
            }
            if (2 * kk + 1 < nt) {
                const f32x4_t p1 = sacc[2 * kk + 1];
                pa.q[1][0] = pack2bf(p1[0] * inv, p1[1] * inv);
                pa.q[1][1] = pack2bf(p1[2] * inv, p1[3] * inv);
            } else {
                pa.q[1][0] = 0u;
                pa.q[1][1] = 0u;
            }
            #pragma unroll
            for (int ni = 0; ni < 4; ni++) {
                FragAB vb;
                const u16* vr = &Vt[(ni * 16 + m) * 264 + kk * 32 + g4];
                vb.q[0] = *(const u32x2*)(vr);
                vb.q[1] = *(const u32x2*)(vr + 16);
                oacc[ni] = __builtin_amdgcn_mfma_f32_16x16x32_bf16(
                    pa.v, vb.v, oacc[ni], 0, 0, 0);
            }
        }

        // O layout: col=lane&15=d, row=(lane>>4)*4+r=q within tile
        #pragma unroll
        for (int ni = 0; ni < 4; ni++) {
            #pragma unroll
            for (int r = 0; r < 4; r++) {
                const int t = rp + (lane >> 4) * 4 + r;
                out[((size_t)row0 + bi * 256 + t) * 384 + h * 64 + ni * 16 + m] =
                    f2bf(oacc[ni][r]);
            }
        }
    }
}

// ---------------------------------------------------------------- launch
extern "C" void kernel_launch(void* const* d_in, const int* in_sizes, int n_in,
                              void* d_out, int out_size, void* d_ws, size_t ws_size,
                              hipStream_t stream)
{
    (void)in_sizes; (void)n_in; (void)out_size;
    const float* x     = (const float*)d_in[0];
    const float* wq    = (const float*)d_in[1];
    const float* wk    = (const float*)d_in[2];
    const float* wv    = (const float*)d_in[3];
    const float* wproj = (const float*)d_in[4];
    const float* bproj = (const float*)d_in[5];
    const float* w1    = (const float*)d_in[6];
    const float* b1    = (const float*)d_in[7];
    const float* w2    = (const float*)d_in[8];
    const float* b2    = (const float*)d_in[9];
    const float* ln1g  = (const float*)d_in[10];
    const float* ln1b  = (const float*)d_in[11];
    const float* ln2g  = (const float*)d_in[12];
    const float* ln2b  = (const float*)d_in[13];
    float* out = (float*)d_out;

    // Fixed region: 28,704,768 B. Dynamic region holds qkv-chunk / mlp1-chunk.
    char* ws = (char*)d_ws;
    u16* hattn  = (u16*)(ws);                 // 25,165,824 B (LN1 out -> attn out -> LN2 out)
    u16* wqkvT  = (u16*)(ws + 25165824);      //    884,736 B
    u16* wprojT = (u16*)(ws + 26050560);      //    294,912 B
    u16* w1T    = (u16*)(ws + 26345472);      //  1,179,648 B
    u16* w2T    = (u16*)(ws + 27525120);      //  1,179,648 B
    char* dyn   = ws + 28704768;
    const size_t avail = (ws_size > (size_t)28704768) ? ws_size - (size_t)28704768 : (size_t)0;

    int na = 32, nm = 32;   // batch-chunk counts for qkv phase / mlp phase
    for (int n = 1; n <= 32; n <<= 1) if ((size_t)75497472  / n <= avail) { na = n; break; }
    for (int n = 1; n <= 32; n <<= 1) if ((size_t)100663296 / n <= avail) { nm = n; break; }

    qkv_w_kernel<<<1728, 256, 0, stream>>>(wq, wk, wv, wqkvT);
    transpose_w_kernel<<<576, 256, 0, stream>>>(wproj, wprojT, 384, 384);
    transpose_w_kernel<<<2304, 256, 0, stream>>>(w1, w1T, 384, 1536);
    transpose_w_kernel<<<2304, 256, 0, stream>>>(w2, w2T, 1536, 384);

    // LN1: x -> h (bf16)
    ln_kernel<<<8192, 256, 0, stream>>>(x, ln1g, ln1b, hattn);

    // QKV gemm + attention, chunked over batches; attn overlays h rows already consumed
    const int rows_a = 32768 / na, bat_a = 128 / na;
    u16* qkvc = (u16*)dyn;
    for (int c = 0; c < na; c++) {
        const int row0 = c * rows_a;
        gemm_kernel<false, false, false, true><<<dim3(9, rows_a / 128), 256, 0, stream>>>(
            hattn + (size_t)row0 * 384, wqkvT, nullptr, nullptr, qkvc, rows_a, 1152, 384);
        attn_kernel<<<bat_a * 6, 256, 0, stream>>>(qkvc, hattn, row0);
    }

    // proj + bias + residual(x) -> out (fp32)
    gemm_kernel<true, true, false, false><<<dim3(3, 256), 256, 0, stream>>>(
        hattn, wprojT, bproj, x, out, 32768, 384, 384);

    // LN2: out -> h (bf16)
    ln_kernel<<<8192, 256, 0, stream>>>(out, ln2g, ln2b, hattn);

    // MLP, chunked: fc1(+bias,relu) -> mlp1 chunk; fc2(+bias,+residual) -> out
    const int rows_m = 32768 / nm;
    u16* mlp1c = (u16*)dyn;
    for (int c = 0; c < nm; c++) {
        const int row0 = c * rows_m;
        gemm_kernel<true, false, true, true><<<dim3(12, rows_m / 128), 256, 0, stream>>>(
            hattn + (size_t)row0 * 384, w1T, b1, nullptr, mlp1c, rows_m, 1536, 384);
        gemm_kernel<true, true, false, false><<<dim3(3, rows_m / 128), 256, 0, stream>>>(
            mlp1c, w2T, b2, out + (size_t)row0 * 384, out + (size_t)row0 * 384,
            rows_m, 384, 1536);
    }
}

// Round 8
// 433.865 us; speedup vs baseline: 1.0904x; 1.0273x over previous
//
#include <hip/hip_runtime.h>
#include <stdint.h>

typedef unsigned short u16;
typedef unsigned int u32;
typedef __bf16 bf16x8_t __attribute__((ext_vector_type(8)));
typedef float f32x4_t __attribute__((ext_vector_type(4)));
typedef unsigned int u32x2 __attribute__((ext_vector_type(2)));
typedef unsigned int u32x4 __attribute__((ext_vector_type(4)));

union FragAB { bf16x8_t v; u32x2 q[2]; };   // b64-pair k-layout (PV path)
union Frag128 { bf16x8_t v; u32x4 q; };     // contiguous b128 k-layout
union Stage16 { u32x4 v; u16 e[8]; };

#define DEVFN static __device__ __forceinline__

DEVFN u16 f2bf(float f) {
    u32 x = __builtin_bit_cast(u32, f);
    return (u16)((x + 0x7fffu + ((x >> 16) & 1u)) >> 16);
}

DEVFN u32 pack2bf(float a, float b) {
    return (u32)f2bf(a) | ((u32)f2bf(b) << 16);
}

DEVFN f32x4_t zero4() { f32x4_t z = {0.f, 0.f, 0.f, 0.f}; return z; }

typedef __attribute__((address_space(1))) void as1_void;
typedef __attribute__((address_space(3))) void as3_void;

#define GLOAD_LDS16(src, dst) \
    __builtin_amdgcn_global_load_lds((as1_void*)(void*)(src), (as3_void*)(dst), 16, 0, 0)

// B=128, T=256, C=384, H=6, D=64; rows = B*T = 32768
#define SCALE_QK 0.051031036307982884f  /* 1/sqrt(384) */
#define NEG_BIG  -30000.0f

// ---------------------------------------------------------------- LayerNorm
__global__ __launch_bounds__(256) void ln_kernel(
        const float* __restrict__ in, const float* __restrict__ g,
        const float* __restrict__ b, u16* __restrict__ out)
{
    const int lane = threadIdx.x & 63;
    const int w = threadIdx.x >> 6;
    const int row = blockIdx.x * 4 + w;
    const float* rp = in + (size_t)row * 384;
    float v[6];
    float s = 0.f, sq = 0.f;
    #pragma unroll
    for (int j = 0; j < 6; j++) {
        v[j] = rp[lane + j * 64];
        s += v[j];
        sq += v[j] * v[j];
    }
    #pragma unroll
    for (int o = 32; o >= 1; o >>= 1) {
        s  += __shfl_xor(s, o);
        sq += __shfl_xor(sq, o);
    }
    const float mean = s * (1.f / 384.f);
    const float var = sq * (1.f / 384.f) - mean * mean;
    const float rs = rsqrtf(var + 1e-5f);
    u16* op = out + (size_t)row * 384;
    #pragma unroll
    for (int j = 0; j < 6; j++) {
        const int c = lane + j * 64;
        op[c] = f2bf((v[j] - mean) * rs * g[c] + b[c]);
    }
}

// ------------------------------------------------------- weight repack (bf16)
__global__ void qkv_w_kernel(const float* __restrict__ wq, const float* __restrict__ wk,
                             const float* __restrict__ wv, u16* __restrict__ bt)
{
    const int idx = blockIdx.x * 256 + threadIdx.x;
    if (idx >= 1152 * 384) return;
    const int j = idx / 384, c = idx % 384;
    const int which = j / 384;
    const int r = j % 384;
    const int h = r / 64, d = r % 64;
    const float* w = (which == 0) ? wq : (which == 1 ? wk : wv);
    bt[idx] = f2bf(w[(h * 384 + c) * 64 + d]);
}

__global__ void transpose_w_kernel(const float* __restrict__ w, u16* __restrict__ bt,
                                   int K, int N)
{
    const int idx = blockIdx.x * 256 + threadIdx.x;
    if (idx >= K * N) return;
    const int n = idx / K, k = idx % K;
    bt[idx] = f2bf(w[(size_t)k * N + n]);
}

// ---------------------------------------------------------------- GEMM
// C[M][N] = A[M][K] * Bt[N][K]^T  (+bias, +res, relu, bf16/f32 out)
// 128x128 tile, BK=64, 4 waves of 64x64, double-buffered 2-phase:
// STAGE(next) issued before COMPUTE(cur); single vmcnt-drain barrier per
// K-step AFTER the MFMAs, so next-tile global_load_lds latency hides under
// compute. Source 16B-chunk index pre-XORed with (row&7); fragment reads are
// single ds_read_b128 with the same XOR (contiguous k, identical for A and B).
template<bool HAS_BIAS, bool HAS_RES, bool RELU, bool OUT_BF16>
__global__ __launch_bounds__(256) void gemm_kernel(
        const u16* __restrict__ A, const u16* __restrict__ Bt,
        const float* __restrict__ bias, const float* __restrict__ res,
        void* __restrict__ Out, int M, int N, int K)
{
    __shared__ u16 As[2][128 * 64];
    __shared__ u16 Bs[2][128 * 64];
    const int tid = threadIdx.x;
    const int lane = tid & 63;
    const int w = tid >> 6;
    const int tileN = blockIdx.x * 128;
    const int tileM = blockIdx.y * 128;
    (void)M;

    f32x4_t acc[4][4];
    #pragma unroll
    for (int i = 0; i < 4; i++)
        #pragma unroll
        for (int j = 0; j < 4; j++)
            acc[i][j] = zero4();

    const int m = lane & 15;
    const int g16 = (lane >> 4) * 16;   // byte offset of contiguous 8-elem k-group

    auto STAGE = [&](int buf, int k0) {
        #pragma unroll
        for (int i = 0; i < 4; i++) {
            const int r = (w * 4 + i) * 8 + (lane >> 3);
            const int sc = (lane & 7) ^ (r & 7);       // 16B-chunk swizzle
            GLOAD_LDS16(A + (size_t)(tileM + r) * K + k0 + sc * 8,
                        (char*)As[buf] + (w * 4 + i) * 1024);
            GLOAD_LDS16(Bt + (size_t)(tileN + r) * K + k0 + sc * 8,
                        (char*)Bs[buf] + (w * 4 + i) * 1024);
        }
    };

    auto COMPUTE = [&](int buf) {
        Frag128 af[4][2], bfb[4][2];
        #pragma unroll
        for (int mi = 0; mi < 4; mi++) {
            const int ar = (w >> 1) * 64 + mi * 16 + m;
            const char* rp = (const char*)As[buf] + ar * 128;
            const int sw = (ar & 7) << 4;
            #pragma unroll
            for (int ks = 0; ks < 2; ks++)
                af[mi][ks].q = *(const u32x4*)(rp + ((ks * 64 + g16) ^ sw));
        }
        #pragma unroll
        for (int ni = 0; ni < 4; ni++) {
            const int br = (w & 1) * 64 + ni * 16 + m;
            const char* rp = (const char*)Bs[buf] + br * 128;
            const int sw = (br & 7) << 4;
            #pragma unroll
            for (int ks = 0; ks < 2; ks++)
                bfb[ni][ks].q = *(const u32x4*)(rp + ((ks * 64 + g16) ^ sw));
        }
        #pragma unroll
        for (int ks = 0; ks < 2; ks++)
            #pragma unroll
            for (int mi = 0; mi < 4; mi++)
                #pragma unroll
                for (int ni = 0; ni < 4; ni++)
                    acc[mi][ni] = __builtin_amdgcn_mfma_f32_16x16x32_bf16(
                        af[mi][ks].v, bfb[ni][ks].v, acc[mi][ni], 0, 0, 0);
    };

    // prologue: stage tile 0, drain, then 2-phase pipeline
    STAGE(0, 0);
    __syncthreads();
    int cur = 0;
    for (int k0 = 64; k0 < K; k0 += 64) {
        STAGE(cur ^ 1, k0);     // next tile in flight across the compute phase
        COMPUTE(cur);
        __syncthreads();        // vmcnt(0)+lgkmcnt(0) drain: next tile ready
        cur ^= 1;
    }
    COMPUTE(cur);               // epilogue tile (no prefetch, no barrier)

    // epilogue: D layout col=lane&15, row=(lane>>4)*4+reg  [verified m89]
    #pragma unroll
    for (int mi = 0; mi < 4; mi++) {
        #pragma unroll
        for (int ni = 0; ni < 4; ni++) {
            #pragma unroll
            for (int r = 0; r < 4; r++) {
                const int grow = tileM + (w >> 1) * 64 + mi * 16 + (lane >> 4) * 4 + r;
                const int gcol = tileN + (w & 1) * 64 + ni * 16 + (lane & 15);
                float v = acc[mi][ni][r];
                if (HAS_BIAS) v += bias[gcol];
                if (HAS_RES) v += res[(size_t)grow * N + gcol];
                if (RELU) v = fmaxf(v, 0.f);
                const size_t o = (size_t)grow * N + gcol;
                if (OUT_BF16) ((u16*)Out)[o] = f2bf(v);
                else ((float*)Out)[o] = v;
            }
        }
    }
}

// ---------------------------------------------------------------- attention
// one block per (local batch, head). qkv: [rows][1152] bf16 chunk (q|k|v per head),
// out: full [32768][384] bf16 base, rows offset by row0.
// Swapped QK^T: S^T = mfma(K, Q) puts a full q-row's k-values lane-local
// (q = lane&15, k = ct*16 + (lane>>4)*4 + r) -> softmax is 2 shfl_xor and
// normalized P packs directly into the PV A-fragment. No P LDS buffer.
__global__ __launch_bounds__(256) void attn_kernel(
        const u16* __restrict__ qkv, u16* __restrict__ out, int row0)
{
    __shared__ u16 Kl[256 * 72];       // K rows [s][d], +8 pad (36,864 B)
    __shared__ u16 Vt[64 * 264];       // V transposed [d][s], +8 pad (33,792 B)

    const int bi = blockIdx.x / 6, h = blockIdx.x % 6;
    const int tid = threadIdx.x, lane = tid & 63, w = tid >> 6;
    const u16* base = qkv + (size_t)bi * 256 * 1152 + h * 64;

    // stage K rows and V^T; each thread covers 8 bf16 = 16 B (u32x4)
    #pragma unroll
    for (int pass = 0; pass < 8; pass++) {
        const int s = pass * 32 + (tid >> 3);
        const int d8 = (tid & 7) * 8;
        const u16* krow = base + (size_t)s * 1152;
        *(u32x4*)(&Kl[s * 72 + d8]) = *(const u32x4*)(krow + 384 + d8);
        Stage16 vv;
        vv.v = *(const u32x4*)(krow + 768 + d8);
        #pragma unroll
        for (int j = 0; j < 8; j++) Vt[(d8 + j) * 264 + s] = vv.e[j];
    }
    __syncthreads();

    const int m = lane & 15;            // q index within row-tile (QK^T), d index (PV)
    const int g4 = (lane >> 4) * 4;     // k-subgroup element offset (b64-pair perm)
    const int g8e = (lane >> 4) * 8;    // contiguous k-group (elements) for d-axis

    for (int p = 0; p < 4; p++) {
        const int rt = p * 4 + w;       // row-tile 0..15
        const int rp = rt * 16;
        const int nt = rt + 1;          // causal: col-tiles needed
        const int qg = rp + m;          // this lane's query row

        // Q fragment (B-operand): row rp+m, d-contiguous 8 elems per reg group
        Frag128 qb[2];
        const u16* qrow = base + (size_t)qg * 1152;
        #pragma unroll
        for (int ks = 0; ks < 2; ks++)
            qb[ks].q = *(const u32x4*)(qrow + ks * 32 + g8e);

        // S^T tiles: sacc[ct] lane layout: q = m, k = ct*16 + g4 + r
        f32x4_t sacc[16];
        #pragma unroll
        for (int ct = 0; ct < 16; ct++) {
            if (ct < nt) {
                sacc[ct] = zero4();
                #pragma unroll
                for (int ks = 0; ks < 2; ks++) {
                    Frag128 kb;
                    kb.q = *(const u32x4*)(&Kl[(ct * 16 + m) * 72 + ks * 32 + g8e]);
                    sacc[ct] = __builtin_amdgcn_mfma_f32_16x16x32_bf16(
                        kb.v, qb[ks].v, sacc[ct], 0, 0, 0);
                }
            }
        }

        // scale + causal mask; all 4*nt values belong to row qg
        float mx = -1e30f;
        #pragma unroll
        for (int ct = 0; ct < 16; ct++) if (ct < nt) {
            #pragma unroll
            for (int r = 0; r < 4; r++) {
                float v = sacc[ct][r] * SCALE_QK;
                if (ct * 16 + g4 + r > qg) v = NEG_BIG;
                sacc[ct][r] = v;
                mx = fmaxf(mx, v);
            }
        }
        mx = fmaxf(mx, __shfl_xor(mx, 16));
        mx = fmaxf(mx, __shfl_xor(mx, 32));

        float sum = 0.f;
        #pragma unroll
        for (int ct = 0; ct < 16; ct++) if (ct < nt) {
            #pragma unroll
            for (int r = 0; r < 4; r++) {
                const float e = __expf(sacc[ct][r] - mx);  // masked -> 0
                sacc[ct][r] = e;
                sum += e;
            }
        }
        sum += __shfl_xor(sum, 16);
        sum += __shfl_xor(sum, 32);
        const float inv = 1.f / sum;

        // O = P V; P fragments built in-register from sacc
        const int kpairs = (nt + 1) >> 1;
        f32x4_t oacc[4];
        #pragma unroll
        for (int ni = 0; ni < 4; ni++) oacc[ni] = zero4();
        #pragma unroll
        for (int kk = 0; kk < 8; kk++) if (kk < kpairs) {
            FragAB pa;
            {
                const f32x4_t p0 = sacc[2 * kk];
                pa.q[0][0] = pack2bf(p0[0] * inv, p0[1] * inv);
                pa.q[0][1] = pack2bf(p0[2] * inv, p0[3] * inv);
            }
            if (2 * kk + 1 < nt) {
                const f32x4_t p1 = sacc[2 * kk + 1];
                pa.q[1][0] = pack2bf(p1[0] * inv, p1[1] * inv);
                pa.q[1][1] = pack2bf(p1[2] * inv, p1[3] * inv);
            } else {
                pa.q[1][0] = 0u;
                pa.q[1][1] = 0u;
            }
            #pragma unroll
            for (int ni = 0; ni < 4; ni++) {
                FragAB vb;
                const u16* vr = &Vt[(ni * 16 + m) * 264 + kk * 32 + g4];
                vb.q[0] = *(const u32x2*)(vr);
                vb.q[1] = *(const u32x2*)(vr + 16);
                oacc[ni] = __builtin_amdgcn_mfma_f32_16x16x32_bf16(
                    pa.v, vb.v, oacc[ni], 0, 0, 0);
            }
        }

        // O layout: col=lane&15=d, row=(lane>>4)*4+r=q within tile
        #pragma unroll
        for (int ni = 0; ni < 4; ni++) {
            #pragma unroll
            for (int r = 0; r < 4; r++) {
                const int t = rp + (lane >> 4) * 4 + r;
                out[((size_t)row0 + bi * 256 + t) * 384 + h * 64 + ni * 16 + m] =
                    f2bf(oacc[ni][r]);
            }
        }
    }
}

// ---------------------------------------------------------------- launch
extern "C" void kernel_launch(void* const* d_in, const int* in_sizes, int n_in,
                              void* d_out, int out_size, void* d_ws, size_t ws_size,
                              hipStream_t stream)
{
    (void)in_sizes; (void)n_in; (void)out_size;
    const float* x     = (const float*)d_in[0];
    const float* wq    = (const float*)d_in[1];
    const float* wk    = (const float*)d_in[2];
    const float* wv    = (const float*)d_in[3];
    const float* wproj = (const float*)d_in[4];
    const float* bproj = (const float*)d_in[5];
    const float* w1    = (const float*)d_in[6];
    const float* b1    = (const float*)d_in[7];
    const float* w2    = (const float*)d_in[8];
    const float* b2    = (const float*)d_in[9];
    const float* ln1g  = (const float*)d_in[10];
    const float* ln1b  = (const float*)d_in[11];
    const float* ln2g  = (const float*)d_in[12];
    const float* ln2b  = (const float*)d_in[13];
    float* out = (float*)d_out;

    // Fixed region: 28,704,768 B. Dynamic region holds qkv-chunk / mlp1-chunk.
    char* ws = (char*)d_ws;
    u16* hattn  = (u16*)(ws);                 // 25,165,824 B (LN1 out -> attn out -> LN2 out)
    u16* wqkvT  = (u16*)(ws + 25165824);      //    884,736 B
    u16* wprojT = (u16*)(ws + 26050560);      //    294,912 B
    u16* w1T    = (u16*)(ws + 26345472);      //  1,179,648 B
    u16* w2T    = (u16*)(ws + 27525120);      //  1,179,648 B
    char* dyn   = ws + 28704768;
    const size_t avail = (ws_size > (size_t)28704768) ? ws_size - (size_t)28704768 : (size_t)0;

    int na = 32, nm = 32;   // batch-chunk counts for qkv phase / mlp phase
    for (int n = 1; n <= 32; n <<= 1) if ((size_t)75497472  / n <= avail) { na = n; break; }
    for (int n = 1; n <= 32; n <<= 1) if ((size_t)100663296 / n <= avail) { nm = n; break; }

    qkv_w_kernel<<<1728, 256, 0, stream>>>(wq, wk, wv, wqkvT);
    transpose_w_kernel<<<576, 256, 0, stream>>>(wproj, wprojT, 384, 384);
    transpose_w_kernel<<<2304, 256, 0, stream>>>(w1, w1T, 384, 1536);
    transpose_w_kernel<<<2304, 256, 0, stream>>>(w2, w2T, 1536, 384);

    // LN1: x -> h (bf16)
    ln_kernel<<<8192, 256, 0, stream>>>(x, ln1g, ln1b, hattn);

    // QKV gemm + attention, chunked over batches; attn overlays h rows already consumed
    const int rows_a = 32768 / na, bat_a = 128 / na;
    u16* qkvc = (u16*)dyn;
    for (int c = 0; c < na; c++) {
        const int row0 = c * rows_a;
        gemm_kernel<false, false, false, true><<<dim3(9, rows_a / 128), 256, 0, stream>>>(
            hattn + (size_t)row0 * 384, wqkvT, nullptr, nullptr, qkvc, rows_a, 1152, 384);
        attn_kernel<<<bat_a * 6, 256, 0, stream>>>(qkvc, hattn, row0);
    }

    // proj + bias + residual(x) -> out (fp32)
    gemm_kernel<true, true, false, false><<<dim3(3, 256), 256, 0, stream>>>(
        hattn, wprojT, bproj, x, out, 32768, 384, 384);

    // LN2: out -> h (bf16)
    ln_kernel<<<8192, 256, 0, stream>>>(out, ln2g, ln2b, hattn);

    // MLP, chunked: fc1(+bias,relu) -> mlp1 chunk; fc2(+bias,+residual) -> out
    const int rows_m = 32768 / nm;
    u16* mlp1c = (u16*)dyn;
    for (int c = 0; c < nm; c++) {
        const int row0 = c * rows_m;
        gemm_kernel<true, false, true, true><<<dim3(12, rows_m / 128), 256, 0, stream>>>(
            hattn + (size_t)row0 * 384, w1T, b1, nullptr, mlp1c, rows_m, 1536, 384);
        gemm_kernel<true, true, false, false><<<dim3(3, rows_m / 128), 256, 0, stream>>>(
            mlp1c, w2T, b2, out + (size_t)row0 * 384, out + (size_t)row0 * 384,
            rows_m, 384, 1536);
    }
}